// Round 4
// baseline (953.900 us; speedup 1.0000x reference)
//
#include <hip/hip_runtime.h>

#define K_IN 256
#define N_OUT 64
#define RPB 256          // rows per bucket
#define MAX_NB 512       // max buckets (supports n <= 131072)
#define MS_CHUNK 4096    // edges per multisplit block

// ---------------- GEMM: XW = X @ W  (fp32 vector, 64x64 tile, 4x4/thread) ---
__global__ __launch_bounds__(256) void gemm_xw(const float* __restrict__ X,
                                               const float* __restrict__ W,
                                               float* __restrict__ XW, int n) {
  __shared__ float Xs[64][68];
  __shared__ float Ws[64][68];
  const int tid = threadIdx.x;
  const int row0 = blockIdx.x * 64;
  const int tx = tid & 15;
  const int ty = tid >> 4;
  float acc[4][4] = {};
  for (int kc = 0; kc < K_IN; kc += 64) {
#pragma unroll
    for (int i = 0; i < 4; ++i) {
      int flat = tid + i * 256;
      int r = flat >> 4;
      int q = flat & 15;
      int gr = row0 + r; if (gr >= n) gr = n - 1;
      float4 xv = *reinterpret_cast<const float4*>(&X[(size_t)gr * K_IN + kc + q * 4]);
      *reinterpret_cast<float4*>(&Xs[r][q * 4]) = xv;
      float4 wv = *reinterpret_cast<const float4*>(&W[(size_t)(kc + r) * N_OUT + q * 4]);
      *reinterpret_cast<float4*>(&Ws[r][q * 4]) = wv;
    }
    __syncthreads();
#pragma unroll
    for (int k = 0; k < 64; ++k) {
      float4 wv = *reinterpret_cast<const float4*>(&Ws[k][tx * 4]);
#pragma unroll
      for (int i = 0; i < 4; ++i) {
        float xv = Xs[ty * 4 + i][k];
        acc[i][0] += xv * wv.x;
        acc[i][1] += xv * wv.y;
        acc[i][2] += xv * wv.z;
        acc[i][3] += xv * wv.w;
      }
    }
    __syncthreads();
  }
#pragma unroll
  for (int i = 0; i < 4; ++i) {
    int gr = row0 + ty * 4 + i;
    if (gr < n) {
      float4 o = make_float4(acc[i][0], acc[i][1], acc[i][2], acc[i][3]);
      *reinterpret_cast<float4*>(&XW[(size_t)gr * N_OUT + tx * 4]) = o;
    }
  }
}

// ---------------- bucket histogram (LDS-privatized) ----------------
__global__ __launch_bounds__(256) void bucket_hist(const int* __restrict__ er,
                                                   int* __restrict__ gh, int E, int NB) {
  __shared__ int h[MAX_NB];
  for (int k = threadIdx.x; k < MAX_NB; k += 256) h[k] = 0;
  __syncthreads();
  for (int i = blockIdx.x * 256 + threadIdx.x; i < E; i += gridDim.x * 256)
    atomicAdd(&h[er[i] >> 8], 1);
  __syncthreads();
  for (int k = threadIdx.x; k < NB; k += 256)
    if (h[k]) atomicAdd(&gh[k], h[k]);
}

// ---------------- exclusive scan of bucket counts (single block) ----------
__global__ __launch_bounds__(256) void scan_small(const int* __restrict__ gh,
    int* __restrict__ boffs, int* __restrict__ gwp, int NB, int E) {
  __shared__ int sc[2][MAX_NB];
  int tid = threadIdx.x;
  for (int k = tid; k < MAX_NB; k += 256) sc[0][k] = (k < NB) ? gh[k] : 0;
  __syncthreads();
  int buf = 0;
  for (int d = 1; d < MAX_NB; d <<= 1) {
    for (int k = tid; k < MAX_NB; k += 256) {
      int v = sc[buf][k];
      if (k >= d) v += sc[buf][k - d];
      sc[buf ^ 1][k] = v;
    }
    buf ^= 1; __syncthreads();
  }
  for (int k = tid; k < NB; k += 256) {
    int ex = (k > 0) ? sc[buf][k - 1] : 0;
    boffs[k] = ex; gwp[k] = ex;
  }
  if (tid == 0) boffs[NB] = E;
}

// ---------------- multisplit: bin edges into bucket-contiguous array -------
// record: int2{ key = (row&255)<<24 | col , valbits }
__global__ __launch_bounds__(256) void multisplit(
    const int* __restrict__ er, const int* __restrict__ ec,
    const float* __restrict__ ev, int* __restrict__ gwp,
    int2* __restrict__ binned, int E) {
  __shared__ int h[MAX_NB];
  __shared__ int sc[2][MAX_NB];
  __shared__ int lsc[MAX_NB];
  __shared__ int base[MAX_NB];
  __shared__ int cursor[MAX_NB];
  __shared__ int2 staged[MS_CHUNK];
  __shared__ unsigned short sbkt[MS_CHUNK];
  const int tid = threadIdx.x;
  const int bb = blockIdx.x * MS_CHUNK;

  for (int k = tid; k < MAX_NB; k += 256) h[k] = 0;
  __syncthreads();

  int rrow[16]; int rcol[16]; float rval[16];
#pragma unroll
  for (int k = 0; k < 16; ++k) {
    int idx = bb + k * 256 + tid;
    if (idx < E) {
      rrow[k] = er[idx]; rcol[k] = ec[idx]; rval[k] = ev[idx];
      atomicAdd(&h[rrow[k] >> 8], 1);
    } else rrow[k] = -1;
  }
  __syncthreads();
  for (int k = tid; k < MAX_NB; k += 256) sc[0][k] = h[k];
  __syncthreads();
  int buf = 0;
  for (int d = 1; d < MAX_NB; d <<= 1) {
    for (int k = tid; k < MAX_NB; k += 256) {
      int v = sc[buf][k];
      if (k >= d) v += sc[buf][k - d];
      sc[buf ^ 1][k] = v;
    }
    buf ^= 1; __syncthreads();
  }
  for (int k = tid; k < MAX_NB; k += 256) {
    int ex = (k > 0) ? sc[buf][k - 1] : 0;
    lsc[k] = ex; cursor[k] = ex;
    int c = h[k];
    base[k] = (c > 0) ? atomicAdd(&gwp[k], c) : 0;
  }
  __syncthreads();
#pragma unroll
  for (int k = 0; k < 16; ++k) {
    if (rrow[k] >= 0) {
      int b = rrow[k] >> 8;
      int pos = atomicAdd(&cursor[b], 1);
      staged[pos] = make_int2(((rrow[k] & 255) << 24) | rcol[k], __float_as_int(rval[k]));
      sbkt[pos] = (unsigned short)b;
    }
  }
  __syncthreads();
  int nv = E - bb; if (nv > MS_CHUNK) nv = MS_CHUNK;
  for (int s = tid; s < nv; s += 256) {
    int b = sbkt[s];
    binned[base[b] + (s - lsc[b])] = staged[s];
  }
}

// ---------------- fused bucket SpMM + bias + ReLU --------------------------
__global__ __launch_bounds__(1024) void bucket_spmm(
    const int* __restrict__ boffs, const int2* __restrict__ binned,
    const float* __restrict__ xw, const float* __restrict__ bias,
    float* __restrict__ out, int n) {
  __shared__ float acc[RPB * N_OUT];  // 64 KB
  const int tid = threadIdx.x;
  const int lane = tid & 63;
  const int wid = tid >> 6;  // 0..15
  const int b = blockIdx.x;
  const int r0 = b * RPB;

  for (int k = tid; k < RPB * N_OUT; k += 1024) acc[k] = 0.f;
  __syncthreads();

  const int s0 = boffs[b], s1 = boffs[b + 1];
  const float bv = bias[lane];

  for (int be = s0 + wid * 64; be < s1; be += 16 * 64) {
    int m = s1 - be; if (m > 64) m = 64;
    int key = 0; float v = 0.f;
    if (lane < m) {
      int2 rec = binned[be + lane];
      key = rec.x; v = __int_as_float(rec.y);
    }
    float pre[8];
#pragma unroll
    for (int j = 0; j < 8; ++j) {
      int c = __shfl(key, j) & 0xFFFFFF;
      pre[j] = xw[(size_t)c * N_OUT + lane];
    }
#pragma unroll
    for (int i = 0; i < 64; i += 8) {
#pragma unroll
      for (int j = 0; j < 8; ++j) {
        int kk = __shfl(key, i + j);
        float vv = __shfl(v, i + j);
        float x = pre[j];
        if (i + 8 < 64) {
          int cn = __shfl(key, i + 8 + j) & 0xFFFFFF;
          pre[j] = xw[(size_t)cn * N_OUT + lane];
        }
        int ri = ((unsigned)kk) >> 24;
        atomicAdd(&acc[ri * N_OUT + lane], vv * x);
      }
    }
  }
  __syncthreads();
#pragma unroll
  for (int k = 0; k < 16; ++k) {
    int lr = wid + k * 16;
    int gr = r0 + lr;
    if (gr < n)
      out[(size_t)gr * N_OUT + lane] = fmaxf(acc[lr * N_OUT + lane] + bv, 0.f);
  }
}

// ---------------- atomic fallback (ws too small) ---------------------------
__global__ void spmm_atomic(const int* __restrict__ er, const int* __restrict__ ec,
                            const float* __restrict__ ev, const float* __restrict__ xw,
                            float* __restrict__ out, int E) {
  int wid = (int)((blockIdx.x * blockDim.x + threadIdx.x) >> 6);
  int lane = threadIdx.x & 63;
  if (wid >= E) return;
  int r = er[wid], c = ec[wid];
  float v = ev[wid];
  atomicAdd(&out[(size_t)r * N_OUT + lane], v * xw[(size_t)c * N_OUT + lane]);
}

__global__ void bias_relu(float* __restrict__ out, const float* __restrict__ bias, int total) {
  int i = blockIdx.x * blockDim.x + threadIdx.x;
  if (i < total) out[i] = fmaxf(out[i] + bias[i & (N_OUT - 1)], 0.f);
}

extern "C" void kernel_launch(void* const* d_in, const int* in_sizes, int n_in,
                              void* d_out, int out_size, void* d_ws, size_t ws_size,
                              hipStream_t stream) {
  const float* X    = (const float*)d_in[0];
  const int*   er   = (const int*)d_in[1];
  const int*   ec   = (const int*)d_in[2];
  const float* ev   = (const float*)d_in[3];
  const float* W    = (const float*)d_in[4];
  const float* bias = (const float*)d_in[5];
  const int n = in_sizes[0] / K_IN;
  const int E = in_sizes[1];
  float* out = (float*)d_out;

  const int NB = (n + RPB - 1) / RPB;

  auto rnd = [](size_t b) { return (b + 255) & ~(size_t)255; };
  const size_t sz_xw     = rnd((size_t)n * N_OUT * 4);
  const size_t sz_gh     = rnd((size_t)MAX_NB * 4);
  const size_t sz_boffs  = rnd((size_t)(MAX_NB + 1) * 4);
  const size_t sz_gwp    = rnd((size_t)MAX_NB * 4);
  const size_t sz_binned = rnd((size_t)E * 8);
  const size_t need = sz_xw + sz_gh + sz_boffs + sz_gwp + sz_binned;

  char* ws = (char*)d_ws;
  float* xw = (float*)ws; ws += sz_xw;

  gemm_xw<<<(n + 63) / 64, 256, 0, stream>>>(X, W, xw, n);

  if (ws_size >= need && NB <= MAX_NB) {
    int*  gh     = (int*)ws;  ws += sz_gh;
    int*  boffs  = (int*)ws;  ws += sz_boffs;
    int*  gwp    = (int*)ws;  ws += sz_gwp;
    int2* binned = (int2*)ws; ws += sz_binned;

    hipMemsetAsync(gh, 0, (size_t)MAX_NB * 4, stream);
    bucket_hist<<<512, 256, 0, stream>>>(er, gh, E, NB);
    scan_small<<<1, 256, 0, stream>>>(gh, boffs, gwp, NB, E);
    multisplit<<<(E + MS_CHUNK - 1) / MS_CHUNK, 256, 0, stream>>>(er, ec, ev, gwp, binned, E);
    bucket_spmm<<<NB, 1024, 0, stream>>>(boffs, binned, xw, bias, out, n);
  } else {
    hipMemsetAsync(out, 0, (size_t)n * N_OUT * 4, stream);
    spmm_atomic<<<(E + 3) / 4, 256, 0, stream>>>(er, ec, ev, xw, out, E);
    bias_relu<<<(n * N_OUT + 255) / 256, 256, 0, stream>>>(out, bias, n * N_OUT);
  }
}

// Round 6
// 929.454 us; speedup vs baseline: 1.0263x; 1.0263x over previous
//
#include <hip/hip_runtime.h>

#define K_IN 256
#define N_OUT 64
#define RPB 128          // rows per bucket
#define MAX_NB 1024      // max buckets (supports n <= 131072)
#define MS_CHUNK 4096    // edges per multisplit block

// ---------------- GEMM: XW = X @ W  (fp32 vector, 64x64 tile, 4x4/thread) ---
__global__ __launch_bounds__(256) void gemm_xw(const float* __restrict__ X,
                                               const float* __restrict__ W,
                                               float* __restrict__ XW, int n) {
  __shared__ float Xs[64][68];
  __shared__ float Ws[64][68];
  const int tid = threadIdx.x;
  const int row0 = blockIdx.x * 64;
  const int tx = tid & 15;
  const int ty = tid >> 4;
  float acc[4][4] = {};
  for (int kc = 0; kc < K_IN; kc += 64) {
#pragma unroll
    for (int i = 0; i < 4; ++i) {
      int flat = tid + i * 256;
      int r = flat >> 4;
      int q = flat & 15;
      int gr = row0 + r; if (gr >= n) gr = n - 1;
      float4 xv = *reinterpret_cast<const float4*>(&X[(size_t)gr * K_IN + kc + q * 4]);
      *reinterpret_cast<float4*>(&Xs[r][q * 4]) = xv;
      float4 wv = *reinterpret_cast<const float4*>(&W[(size_t)(kc + r) * N_OUT + q * 4]);
      *reinterpret_cast<float4*>(&Ws[r][q * 4]) = wv;
    }
    __syncthreads();
#pragma unroll
    for (int k = 0; k < 64; ++k) {
      float4 wv = *reinterpret_cast<const float4*>(&Ws[k][tx * 4]);
#pragma unroll
      for (int i = 0; i < 4; ++i) {
        float xv = Xs[ty * 4 + i][k];
        acc[i][0] += xv * wv.x;
        acc[i][1] += xv * wv.y;
        acc[i][2] += xv * wv.z;
        acc[i][3] += xv * wv.w;
      }
    }
    __syncthreads();
  }
#pragma unroll
  for (int i = 0; i < 4; ++i) {
    int gr = row0 + ty * 4 + i;
    if (gr < n) {
      float4 o = make_float4(acc[i][0], acc[i][1], acc[i][2], acc[i][3]);
      *reinterpret_cast<float4*>(&XW[(size_t)gr * N_OUT + tx * 4]) = o;
    }
  }
}

// ---------------- bucket histogram (LDS-privatized) ----------------
__global__ __launch_bounds__(256) void bucket_hist(const int* __restrict__ er,
                                                   int* __restrict__ gh, int E, int NB) {
  __shared__ int h[MAX_NB];
  for (int k = threadIdx.x; k < MAX_NB; k += 256) h[k] = 0;
  __syncthreads();
  for (int i = blockIdx.x * 256 + threadIdx.x; i < E; i += gridDim.x * 256)
    atomicAdd(&h[er[i] >> 7], 1);
  __syncthreads();
  for (int k = threadIdx.x; k < NB; k += 256)
    if (h[k]) atomicAdd(&gh[k], h[k]);
}

// ---------------- exclusive scan of bucket counts (single block) ----------
__global__ __launch_bounds__(256) void scan_small(const int* __restrict__ gh,
    int* __restrict__ boffs, int* __restrict__ gwp, int NB, int E) {
  __shared__ int sc[2][MAX_NB];
  int tid = threadIdx.x;
  for (int k = tid; k < MAX_NB; k += 256) sc[0][k] = (k < NB) ? gh[k] : 0;
  __syncthreads();
  int buf = 0;
  for (int d = 1; d < MAX_NB; d <<= 1) {
    for (int k = tid; k < MAX_NB; k += 256) {
      int v = sc[buf][k];
      if (k >= d) v += sc[buf][k - d];
      sc[buf ^ 1][k] = v;
    }
    buf ^= 1; __syncthreads();
  }
  for (int k = tid; k < NB; k += 256) {
    int ex = (k > 0) ? sc[buf][k - 1] : 0;
    boffs[k] = ex; gwp[k] = ex;
  }
  if (tid == 0) boffs[NB] = E;
}

// ---------------- multisplit: bin edges into bucket-contiguous array -------
// record: int2{ key = (row&127)<<24 | col , valbits }
__global__ __launch_bounds__(256) void multisplit(
    const int* __restrict__ er, const int* __restrict__ ec,
    const float* __restrict__ ev, int* __restrict__ gwp,
    int2* __restrict__ binned, int E) {
  __shared__ int h[MAX_NB];
  __shared__ int sc[2][MAX_NB];
  __shared__ int lsc[MAX_NB];
  __shared__ int base[MAX_NB];
  __shared__ int cursor[MAX_NB];
  __shared__ int2 staged[MS_CHUNK];
  __shared__ unsigned short sbkt[MS_CHUNK];
  const int tid = threadIdx.x;
  const int bb = blockIdx.x * MS_CHUNK;

  for (int k = tid; k < MAX_NB; k += 256) h[k] = 0;
  __syncthreads();

  int rrow[16]; int rcol[16]; float rval[16];
#pragma unroll
  for (int k = 0; k < 16; ++k) {
    int idx = bb + k * 256 + tid;
    if (idx < E) {
      rrow[k] = er[idx]; rcol[k] = ec[idx]; rval[k] = ev[idx];
      atomicAdd(&h[rrow[k] >> 7], 1);
    } else rrow[k] = -1;
  }
  __syncthreads();
  for (int k = tid; k < MAX_NB; k += 256) sc[0][k] = h[k];
  __syncthreads();
  int buf = 0;
  for (int d = 1; d < MAX_NB; d <<= 1) {
    for (int k = tid; k < MAX_NB; k += 256) {
      int v = sc[buf][k];
      if (k >= d) v += sc[buf][k - d];
      sc[buf ^ 1][k] = v;
    }
    buf ^= 1; __syncthreads();
  }
  for (int k = tid; k < MAX_NB; k += 256) {
    int ex = (k > 0) ? sc[buf][k - 1] : 0;
    lsc[k] = ex; cursor[k] = ex;
    int c = h[k];
    base[k] = (c > 0) ? atomicAdd(&gwp[k], c) : 0;
  }
  __syncthreads();
#pragma unroll
  for (int k = 0; k < 16; ++k) {
    if (rrow[k] >= 0) {
      int b = rrow[k] >> 7;
      int pos = atomicAdd(&cursor[b], 1);
      staged[pos] = make_int2(((rrow[k] & 127) << 24) | rcol[k], __float_as_int(rval[k]));
      sbkt[pos] = (unsigned short)b;
    }
  }
  __syncthreads();
  int nv = E - bb; if (nv > MS_CHUNK) nv = MS_CHUNK;
  for (int s = tid; s < nv; s += 256) {
    int b = sbkt[s];
    binned[base[b] + (s - lsc[b])] = staged[s];
  }
}

// ---------------- fused bucket SpMM + bias + ReLU --------------------------
// wave processes 64 records/batch in 16 passes of 4 records; lane role:
// sub = lane>>4 (record within pass), q = lane&15 (float4 chunk of the row).
// acc bank rotation: logical (ri,f) stored at ri*64 + ((f + 4*(ri&15)) & 63).
#define PREP(p) \
  int kk##p = __shfl(key, 4 * (p) + sub); \
  float vv##p = __shfl(val, 4 * (p) + sub); \
  float4 g##p = *reinterpret_cast<const float4*>( \
      &xw[((size_t)(kk##p & 0xFFFFFF) << 6) + (q << 2)]);

#define CONS(p) { \
  int ri = ((unsigned)kk##p) >> 24; \
  int off0 = ((q << 2) + ((ri & 15) << 2)) & 63; \
  float* ap = &acc[(ri << 6) + off0]; \
  atomicAdd(&ap[0], vv##p * g##p.x); \
  atomicAdd(&ap[1], vv##p * g##p.y); \
  atomicAdd(&ap[2], vv##p * g##p.z); \
  atomicAdd(&ap[3], vv##p * g##p.w); }

__global__ __launch_bounds__(256, 4) void bucket_spmm(
    const int* __restrict__ boffs, const int2* __restrict__ binned,
    const float* __restrict__ xw, const float* __restrict__ bias,
    float* __restrict__ out, int n) {
  __shared__ float acc[RPB * N_OUT];  // 32 KB
  const int tid = threadIdx.x;
  const int lane = tid & 63;
  const int wid = tid >> 6;  // 0..3
  const int sub = lane >> 4;
  const int q = lane & 15;
  const int b = blockIdx.x;
  const int r0 = b * RPB;

  for (int k = tid; k < RPB * N_OUT; k += 256) acc[k] = 0.f;
  __syncthreads();

  const int s0 = boffs[b], s1 = boffs[b + 1];

  for (int be = s0 + wid * 64; be < s1; be += 4 * 64) {
    int m = s1 - be; if (m > 64) m = 64;
    int2 rec = make_int2(0, 0);
    if (lane < m) rec = binned[be + lane];      // key=0,val=0 pad: adds 0.0f
    int key = rec.x; float val = __int_as_float(rec.y);

    PREP(0) PREP(1) PREP(2) PREP(3) PREP(4) PREP(5) PREP(6) PREP(7)
    CONS(0) PREP(8)
    CONS(1) PREP(9)
    CONS(2) PREP(10)
    CONS(3) PREP(11)
    CONS(4) PREP(12)
    CONS(5) PREP(13)
    CONS(6) PREP(14)
    CONS(7) PREP(15)
    CONS(8) CONS(9) CONS(10) CONS(11) CONS(12) CONS(13) CONS(14) CONS(15)
  }
  __syncthreads();

  const float bv = bias[tid & 63];
#pragma unroll
  for (int k = 0; k < 32; ++k) {
    int idx = tid + k * 256;          // 0..8191
    int lr = idx >> 6;                // row in bucket; one row per wave per k
    int f = idx & 63;
    int gr = r0 + lr;
    if (gr < n) {
      float v = acc[(lr << 6) + ((f + ((lr & 15) << 2)) & 63)];
      out[(size_t)gr * N_OUT + f] = fmaxf(v + bv, 0.f);
    }
  }
}

// ---------------- atomic fallback (ws too small) ---------------------------
__global__ void spmm_atomic(const int* __restrict__ er, const int* __restrict__ ec,
                            const float* __restrict__ ev, const float* __restrict__ xw,
                            float* __restrict__ out, int E) {
  int wid = (int)((blockIdx.x * blockDim.x + threadIdx.x) >> 6);
  int lane = threadIdx.x & 63;
  if (wid >= E) return;
  int r = er[wid], c = ec[wid];
  float v = ev[wid];
  atomicAdd(&out[(size_t)r * N_OUT + lane], v * xw[(size_t)c * N_OUT + lane]);
}

__global__ void bias_relu(float* __restrict__ out, const float* __restrict__ bias, int total) {
  int i = blockIdx.x * blockDim.x + threadIdx.x;
  if (i < total) out[i] = fmaxf(out[i] + bias[i & (N_OUT - 1)], 0.f);
}

extern "C" void kernel_launch(void* const* d_in, const int* in_sizes, int n_in,
                              void* d_out, int out_size, void* d_ws, size_t ws_size,
                              hipStream_t stream) {
  const float* X    = (const float*)d_in[0];
  const int*   er   = (const int*)d_in[1];
  const int*   ec   = (const int*)d_in[2];
  const float* ev   = (const float*)d_in[3];
  const float* W    = (const float*)d_in[4];
  const float* bias = (const float*)d_in[5];
  const int n = in_sizes[0] / K_IN;
  const int E = in_sizes[1];
  float* out = (float*)d_out;

  const int NB = (n + RPB - 1) / RPB;

  auto rnd = [](size_t b) { return (b + 255) & ~(size_t)255; };
  const size_t sz_xw     = rnd((size_t)n * N_OUT * 4);
  const size_t sz_gh     = rnd((size_t)MAX_NB * 4);
  const size_t sz_boffs  = rnd((size_t)(MAX_NB + 1) * 4);
  const size_t sz_gwp    = rnd((size_t)MAX_NB * 4);
  const size_t sz_binned = rnd((size_t)E * 8);
  const size_t need = sz_xw + sz_gh + sz_boffs + sz_gwp + sz_binned;

  char* ws = (char*)d_ws;
  float* xw = (float*)ws; ws += sz_xw;

  gemm_xw<<<(n + 63) / 64, 256, 0, stream>>>(X, W, xw, n);

  if (ws_size >= need && NB <= MAX_NB) {
    int*  gh     = (int*)ws;  ws += sz_gh;
    int*  boffs  = (int*)ws;  ws += sz_boffs;
    int*  gwp    = (int*)ws;  ws += sz_gwp;
    int2* binned = (int2*)ws; ws += sz_binned;

    hipMemsetAsync(gh, 0, (size_t)MAX_NB * 4, stream);
    bucket_hist<<<512, 256, 0, stream>>>(er, gh, E, NB);
    scan_small<<<1, 256, 0, stream>>>(gh, boffs, gwp, NB, E);
    multisplit<<<(E + MS_CHUNK - 1) / MS_CHUNK, 256, 0, stream>>>(er, ec, ev, gwp, binned, E);
    bucket_spmm<<<NB, 256, 0, stream>>>(boffs, binned, xw, bias, out, n);
  } else {
    hipMemsetAsync(out, 0, (size_t)n * N_OUT * 4, stream);
    spmm_atomic<<<(E + 3) / 4, 256, 0, stream>>>(er, ec, ev, xw, out, E);
    bias_relu<<<(n * N_OUT + 255) / 256, 256, 0, stream>>>(out, bias, n * N_OUT);
  }
}